// Round 8
// baseline (448.521 us; speedup 1.0000x reference)
//
#include <hip/hip_runtime.h>

// clang-native vector types: __builtin_nontemporal_* rejects HIP_vector_type wrappers.
typedef int nt_int4 __attribute__((ext_vector_type(4)));

#define NB     256        // vertex buckets (== bin block threads)
#define VSHIFT 12         // 4096 verts per bucket -> 16 KB LDS table
#define BMASK  ((1 << VSHIFT) - 1)
#define BCAP   65536      // pairs per bucket capacity (mean 62.5K + 12 sigma)
#define RT     2          // tets per thread per round (pipelined regs stay < 64 VGPR)
#define NR     4          // rounds -> 2048 tets per block; grid ~1954 = 7.6 blocks/CU
                          // (round-7 lesson: NR=8 gave 977 blocks -> 38% occupancy)

// Fused setup: zero vd region (harness poisons d_out), zero bucket counters,
// pad 12B-strided verts to 16B float4 (one launch instead of two).
__global__ __launch_bounds__(256) void setup_kernel(uint4* __restrict__ vd4, int n4,
                                                    unsigned* __restrict__ gcnt,
                                                    const float* __restrict__ verts,
                                                    float4* __restrict__ verts4, int V) {
    int i = blockIdx.x * blockDim.x + threadIdx.x;
    if (i < n4) vd4[i] = make_uint4(0u, 0u, 0u, 0u);
    if (gcnt && i < NB) gcnt[i] = 0u;
    if (verts4 && i < V) {
        const float* p = verts + (size_t)i * 3;
        verts4[i] = make_float4(p[0], p[1], p[2], 0.f);
    }
}

// ---- fused geometry + binning, software-pipelined, occupancy-sized ----
__global__ __launch_bounds__(256) void fused_geom_bin_kernel(
    const float4* __restrict__ verts4,
    const int4*  __restrict__ idx4,
    const float* __restrict__ dens,
    float* __restrict__ out_area,
    float* __restrict__ out_alpha,
    uint2*       __restrict__ pairs,   // NB x BCAP
    unsigned*    __restrict__ gcnt,    // NB
    unsigned*    __restrict__ vd,      // overflow fallback target (zeroed)
    int T)
{
    __shared__ unsigned s_cnt[NB];
    __shared__ unsigned s_run[NB];
    __shared__ unsigned s_roff[NB];
    __shared__ unsigned s_wc[NB];
    __shared__ unsigned s_wsum[4];
    __shared__ uint2    stage[256 * RT * 4];   // 2048 pairs = 16 KB; total LDS ~20.5 KB

    int tid  = threadIdx.x;
    int lane = tid & 63;
    int wid  = tid >> 6;
    int base = blockIdx.x * (256 * RT * NR);

    // phase 1: count the block chunk. Plain cached loads: the rounds re-read the
    // same idx lines from L2 (round-7's nontemporal here defeated that).
    s_cnt[tid] = 0u;
    __syncthreads();
    for (int k = 0; k < RT * NR; ++k) {
        int i = base + k * 256 + tid;
        if (i < T) {
            int4 q = idx4[i];
            atomicAdd(&s_cnt[(unsigned)q.x >> VSHIFT], 1u);
            atomicAdd(&s_cnt[(unsigned)q.y >> VSHIFT], 1u);
            atomicAdd(&s_cnt[(unsigned)q.z >> VSHIFT], 1u);
            atomicAdd(&s_cnt[(unsigned)q.w >> VSHIFT], 1u);
        }
    }
    __syncthreads();

    // phase 2: one global bump per (block, bucket)
    s_run[tid] = atomicAdd(&gcnt[tid], s_cnt[tid]);
    __syncthreads();

    // pipeline registers
    int4  q[RT], qn[RT];
    float dd[RT], ddn[RT];
    bool  vl[RT], vln[RT];
    float4 pv[RT][4];

    // prologue: round-0 idx/dens + gathers
#pragma unroll
    for (int k = 0; k < RT; ++k) {
        int i = base + k * 256 + tid;
        vl[k] = (i < T);
        if (vl[k]) { q[k] = idx4[i]; dd[k] = dens[i]; }
    }
#pragma unroll
    for (int k = 0; k < RT; ++k) if (vl[k]) {
        pv[k][0] = verts4[q[k].x];
        pv[k][1] = verts4[q[k].y];
        pv[k][2] = verts4[q[k].z];
        pv[k][3] = verts4[q[k].w];
    }

    for (int r = 0; r < NR; ++r) {
        // 1. prefetch next round's idx/dens
        if (r + 1 < NR) {
#pragma unroll
            for (int k = 0; k < RT; ++k) {
                int i = base + ((r + 1) * RT + k) * 256 + tid;
                vln[k] = (i < T);
                if (vln[k]) { qn[k] = idx4[i]; ddn[k] = dens[i]; }
            }
        }

        // 2. geometry (consumes pv loaded during previous round's LDS phases)
#pragma unroll
        for (int k = 0; k < RT; ++k) if (vl[k]) {
            int i = base + (r * RT + k) * 256 + tid;
            float4 v0 = pv[k][0], v1 = pv[k][1], v2 = pv[k][2], v3 = pv[k][3];

            float e1x = v1.x - v0.x, e1y = v1.y - v0.y, e1z = v1.z - v0.z;
            float e2x = v2.x - v0.x, e2y = v2.y - v0.y, e2z = v2.z - v0.z;
            float e3x = v3.x - v0.x, e3y = v3.y - v0.y, e3z = v3.z - v0.z;

            float det = e1x * (e2y * e3z - e2z * e3y)
                      - e1y * (e2x * e3z - e2z * e3x)
                      + e1z * (e2x * e3y - e2y * e3x);
            __builtin_nontemporal_store(fabsf(det) * (1.0f / 6.0f), &out_area[i]);

            float q01 = e1x * e1x + e1y * e1y + e1z * e1z;
            float q02 = e2x * e2x + e2y * e2y + e2z * e2z;
            float q03 = e3x * e3x + e3y * e3y + e3z * e3z;
            float ax, ay, az;
            ax = v1.x - v2.x; ay = v1.y - v2.y; az = v1.z - v2.z;
            float q12 = ax * ax + ay * ay + az * az;
            ax = v1.x - v3.x; ay = v1.y - v3.y; az = v1.z - v3.z;
            float q13 = ax * ax + ay * ay + az * az;
            ax = v2.x - v3.x; ay = v2.y - v3.y; az = v2.z - v3.z;
            float q23 = ax * ax + ay * ay + az * az;

            float mn = fminf(fminf(fminf(q01, q02), fminf(q03, q12)), fminf(q13, q23));
            float el = sqrtf(mn);
            __builtin_nontemporal_store(1.0f - expf(-dd[k] * el), &out_alpha[i]);
        }

        // 3. round histogram
        s_cnt[tid] = 0u;
        __syncthreads();
#pragma unroll
        for (int k = 0; k < RT; ++k) if (vl[k]) {
            atomicAdd(&s_cnt[(unsigned)q[k].x >> VSHIFT], 1u);
            atomicAdd(&s_cnt[(unsigned)q[k].y >> VSHIFT], 1u);
            atomicAdd(&s_cnt[(unsigned)q[k].z >> VSHIFT], 1u);
            atomicAdd(&s_cnt[(unsigned)q[k].w >> VSHIFT], 1u);
        }
        __syncthreads();

        // 4. wave-shuffle exclusive scan (2 barriers)
        unsigned x = s_cnt[tid];
        unsigned incl = x;
#pragma unroll
        for (int s = 1; s < 64; s <<= 1) {
            unsigned t = __shfl_up(incl, s);
            if (lane >= s) incl += t;
        }
        if (lane == 63) s_wsum[wid] = incl;
        __syncthreads();
        unsigned pre = 0;
#pragma unroll
        for (int w = 0; w < 4; ++w) pre += (w < wid) ? s_wsum[w] : 0u;
        unsigned npairs = s_wsum[0] + s_wsum[1] + s_wsum[2] + s_wsum[3];
        s_roff[tid] = pre + incl - x;
        s_wc[tid]   = 0u;
        __syncthreads();

        // 5. issue next round's vertex gathers (pv dead after step 2)
        if (r + 1 < NR) {
#pragma unroll
            for (int k = 0; k < RT; ++k) if (vln[k]) {
                pv[k][0] = verts4[qn[k].x];
                pv[k][1] = verts4[qn[k].y];
                pv[k][2] = verts4[qn[k].z];
                pv[k][3] = verts4[qn[k].w];
            }
        }

        // 6. scatter round pairs into bucket-compacted staging
#pragma unroll
        for (int k = 0; k < RT; ++k) if (vl[k]) {
            unsigned db = __float_as_uint(dd[k]);
            unsigned vv[4] = { (unsigned)q[k].x, (unsigned)q[k].y,
                               (unsigned)q[k].z, (unsigned)q[k].w };
#pragma unroll
            for (int j = 0; j < 4; ++j) {
                unsigned b    = vv[j] >> VSHIFT;
                unsigned slot = s_roff[b] + atomicAdd(&s_wc[b], 1u);
                stage[slot] = make_uint2(vv[j], db);
            }
        }
        __syncthreads();

        // 7. coalesced flush: lane-consecutive staging slots -> consecutive global
        for (unsigned l = tid; l < npairs; l += 256) {
            uint2 e = stage[l];
            unsigned b  = e.x >> VSHIFT;
            unsigned rr = s_run[b] + (l - s_roff[b]);
            if (rr < BCAP) pairs[(size_t)b * BCAP + rr] = e;
            else           atomicMax(vd + e.x, e.y); // astronomically rare; correct
        }
        __syncthreads();

        // 8. advance running bases and rotate pipeline registers
        s_run[tid] += s_cnt[tid];
#pragma unroll
        for (int k = 0; k < RT; ++k) { q[k] = qn[k]; dd[k] = ddn[k]; vl[k] = vln[k]; }
    }
}

// ---- per-bucket max in LDS: zero global atomics ----
__global__ __launch_bounds__(1024) void bucket_max_kernel(
    const uint2*    __restrict__ pairs,
    const unsigned* __restrict__ gcnt,
    unsigned*       __restrict__ vd,
    int V)
{
    __shared__ unsigned tbl[1 << VSHIFT];
    int b   = blockIdx.x;
    int tid = threadIdx.x;

    for (int j = tid; j < (1 << VSHIFT); j += 1024) tbl[j] = 0u;
    __syncthreads();

    unsigned cnt = gcnt[b];
    if (cnt > BCAP) cnt = BCAP;
    const uint2* p = pairs + (size_t)b * BCAP;
    for (unsigned i = tid; i < cnt; i += 1024) {
        uint2 e = p[i];
        atomicMax(&tbl[e.x & BMASK], e.y);   // ds_max_u32: on-chip
    }
    __syncthreads();

    int vbase = b << VSHIFT;
    for (int j = tid; j < (1 << VSHIFT); j += 1024) {
        int v = vbase + j;
        if (v < V) {
            unsigned cur = vd[v];            // merge overflow-fallback atomics
            unsigned t   = tbl[j];
            vd[v] = cur > t ? cur : t;
        }
    }
}

// ---------------- tier-3: round-3 verified kernel (read-filtered atomics) ----------------
__global__ __launch_bounds__(256) void tet_kernel_filter(
    const float4* __restrict__ verts4,
    const int*   __restrict__ indices,
    const float* __restrict__ density,
    float* __restrict__ out_area,
    float* __restrict__ out_alpha,
    unsigned int* __restrict__ vd,
    int T)
{
    int i = blockIdx.x * blockDim.x + threadIdx.x;
    if (i >= T) return;

    nt_int4 idx = __builtin_nontemporal_load((const nt_int4*)indices + i);
    float d     = __builtin_nontemporal_load(&density[i]);
    unsigned int db = __float_as_uint(d);

    unsigned int c0 = vd[idx.x];
    unsigned int c1 = vd[idx.y];
    unsigned int c2 = vd[idx.z];
    unsigned int c3 = vd[idx.w];

    float4 v0 = verts4[idx.x];
    float4 v1 = verts4[idx.y];
    float4 v2 = verts4[idx.z];
    float4 v3 = verts4[idx.w];

    float e1x = v1.x - v0.x, e1y = v1.y - v0.y, e1z = v1.z - v0.z;
    float e2x = v2.x - v0.x, e2y = v2.y - v0.y, e2z = v2.z - v0.z;
    float e3x = v3.x - v0.x, e3y = v3.y - v0.y, e3z = v3.z - v0.z;

    float det = e1x * (e2y * e3z - e2z * e3y)
              - e1y * (e2x * e3z - e2z * e3x)
              + e1z * (e2x * e3y - e2y * e3x);
    __builtin_nontemporal_store(fabsf(det) * (1.0f / 6.0f), &out_area[i]);

    float q01 = e1x * e1x + e1y * e1y + e1z * e1z;
    float q02 = e2x * e2x + e2y * e2y + e2z * e2z;
    float q03 = e3x * e3x + e3y * e3y + e3z * e3z;
    float ax, ay, az;
    ax = v1.x - v2.x; ay = v1.y - v2.y; az = v1.z - v2.z;
    float q12 = ax * ax + ay * ay + az * az;
    ax = v1.x - v3.x; ay = v1.y - v3.y; az = v1.z - v3.z;
    float q13 = ax * ax + ay * ay + az * az;
    ax = v2.x - v3.x; ay = v2.y - v3.y; az = v2.z - v3.z;
    float q23 = ax * ax + ay * ay + az * az;

    float mn = fminf(fminf(fminf(q01, q02), fminf(q03, q12)), fminf(q13, q23));
    float el = sqrtf(mn);
    __builtin_nontemporal_store(1.0f - expf(-d * el), &out_alpha[i]);

    if (db > c0) atomicMax(vd + idx.x, db);
    if (db > c1) atomicMax(vd + idx.y, db);
    if (db > c2) atomicMax(vd + idx.z, db);
    if (db > c3) atomicMax(vd + idx.w, db);
}

// ---------------- tier-4: round-0 verified kernel ----------------
__global__ __launch_bounds__(256) void tet_kernel_fb(
    const float* __restrict__ verts,
    const int4*  __restrict__ indices,
    const float* __restrict__ density,
    float* __restrict__ out_area,
    float* __restrict__ out_alpha,
    unsigned int* __restrict__ vd,
    int T)
{
    int i = blockIdx.x * blockDim.x + threadIdx.x;
    if (i >= T) return;

    int4 idx = indices[i];
    float d = density[i];

    const float* p;
    p = verts + idx.x * 3; float v0x = p[0], v0y = p[1], v0z = p[2];
    p = verts + idx.y * 3; float v1x = p[0], v1y = p[1], v1z = p[2];
    p = verts + idx.z * 3; float v2x = p[0], v2y = p[1], v2z = p[2];
    p = verts + idx.w * 3; float v3x = p[0], v3y = p[1], v3z = p[2];

    float e1x = v1x - v0x, e1y = v1y - v0y, e1z = v1z - v0z;
    float e2x = v2x - v0x, e2y = v2y - v0y, e2z = v2z - v0z;
    float e3x = v3x - v0x, e3y = v3y - v0y, e3z = v3z - v0z;

    float det = e1x * (e2y * e3z - e2z * e3y)
              - e1y * (e2x * e3z - e2z * e3x)
              + e1z * (e2x * e3y - e2y * e3x);
    out_area[i] = fabsf(det) * (1.0f / 6.0f);

    float q01 = e1x * e1x + e1y * e1y + e1z * e1z;
    float q02 = e2x * e2x + e2y * e2y + e2z * e2z;
    float q03 = e3x * e3x + e3y * e3y + e3z * e3z;
    float ax, ay, az;
    ax = v1x - v2x; ay = v1y - v2y; az = v1z - v2z;
    float q12 = ax * ax + ay * ay + az * az;
    ax = v1x - v3x; ay = v1y - v3y; az = v1z - v3z;
    float q13 = ax * ax + ay * ay + az * az;
    ax = v2x - v3x; ay = v2y - v3y; az = v2z - v3z;
    float q23 = ax * ax + ay * ay + az * az;

    float mn = fminf(fminf(fminf(q01, q02), fminf(q03, q12)), fminf(q13, q23));
    float el = sqrtf(mn);
    out_alpha[i] = 1.0f - expf(-d * el);

    unsigned int db = __float_as_uint(d);
    atomicMax(vd + idx.x, db);
    atomicMax(vd + idx.y, db);
    atomicMax(vd + idx.z, db);
    atomicMax(vd + idx.w, db);
}

// ---------------- launch ----------------

extern "C" void kernel_launch(void* const* d_in, const int* in_sizes, int n_in,
                              void* d_out, int out_size, void* d_ws, size_t ws_size,
                              hipStream_t stream) {
    const float* verts   = (const float*)d_in[0];
    const int*   indices = (const int*)d_in[1];
    const float* density = (const float*)d_in[2];
    int T = in_sizes[2];        // 4,000,000 tets
    int V = in_sizes[0] / 3;    // 1,000,000 vertices

    float* out       = (float*)d_out;
    float* out_area  = out;
    float* out_alpha = out + (size_t)T;
    unsigned int* vd = (unsigned int*)(out + 2 * (size_t)T);

    const int block = 256;
    int n4 = V / 4;

    size_t pairsB = (size_t)NB * BCAP * sizeof(uint2);   // 128 MB
    size_t cntB   = (size_t)NB * sizeof(unsigned);
    size_t v4B    = (size_t)V * sizeof(float4);          // 16 MB

    double mean = 4.0 * (double)T / NB;
    bool capOK = (mean + 12.0 * __builtin_sqrt(mean) <= (double)BCAP);
    bool fastOK = (V % 4 == 0) && (V <= (NB << VSHIFT)) && capOK && d_ws;

    int tetsPerBlock = block * RT * NR;   // 2048
    int nbAct = (V + (1 << VSHIFT) - 1) >> VSHIFT;

    if (fastOK && ws_size >= pairsB + cntB + v4B) {
        uint2*    pairs  = (uint2*)d_ws;
        unsigned* gcnt   = (unsigned*)((char*)d_ws + pairsB);
        float4*   verts4 = (float4*)((char*)d_ws + pairsB + ((cntB + 255) & ~(size_t)255));

        int setupN = (V > n4 ? V : n4);
        setup_kernel<<<(setupN + block - 1) / block, block, 0, stream>>>(
            (uint4*)vd, n4, gcnt, verts, verts4, V);

        fused_geom_bin_kernel<<<(T + tetsPerBlock - 1) / tetsPerBlock, block, 0, stream>>>(
            verts4, (const int4*)indices, density, out_area, out_alpha, pairs, gcnt, vd, T);

        bucket_max_kernel<<<nbAct, 1024, 0, stream>>>(pairs, gcnt, vd, V);
    } else if (d_ws && ws_size >= v4B && (V % 4) == 0) {
        // tier-3: round-3 verified path
        float4* verts4 = (float4*)d_ws;
        int setupN = (V > n4 ? V : n4);
        setup_kernel<<<(setupN + block - 1) / block, block, 0, stream>>>(
            (uint4*)vd, n4, nullptr, verts, verts4, V);
        tet_kernel_filter<<<(T + block - 1) / block, block, 0, stream>>>(
            verts4, indices, density, out_area, out_alpha, vd, T);
    } else {
        // tier-4: round-0 verified path
        setup_kernel<<<(n4 + block - 1) / block, block, 0, stream>>>(
            (uint4*)vd, n4, nullptr, nullptr, nullptr, 0);
        tet_kernel_fb<<<(T + block - 1) / block, block, 0, stream>>>(
            verts, (const int4*)indices, density, out_area, out_alpha, vd, T);
    }
}

// Round 9
// 434.068 us; speedup vs baseline: 1.0333x; 1.0333x over previous
//
#include <hip/hip_runtime.h>

// clang-native vector types: __builtin_nontemporal_* rejects HIP_vector_type wrappers.
typedef int          nt_int4  __attribute__((ext_vector_type(4)));
typedef unsigned int nt_uint2 __attribute__((ext_vector_type(2)));

#define NB     256        // vertex buckets (== bin block threads)
#define VSHIFT 12         // 4096 verts per bucket -> 16 KB LDS table
#define BMASK  ((1 << VSHIFT) - 1)
#define BCAP   65536      // pairs per bucket capacity (mean 62.5K + 12 sigma)
#define RT     4          // tets per thread per round (16 gathers in flight: measured best)
#define NR     4          // rounds -> 4096 tets per block (round-6 config: 306 us;
                          // RT=2 variants measured 315/330 -> ILP beats occupancy here)

// Fused setup: zero vd region (harness poisons d_out), zero bucket counters,
// pad 12B-strided verts to 16B float4.
__global__ __launch_bounds__(256) void setup_kernel(uint4* __restrict__ vd4, int n4,
                                                    unsigned* __restrict__ gcnt,
                                                    const float* __restrict__ verts,
                                                    float4* __restrict__ verts4, int V) {
    int i = blockIdx.x * blockDim.x + threadIdx.x;
    if (i < n4) vd4[i] = make_uint4(0u, 0u, 0u, 0u);
    if (gcnt && i < NB) gcnt[i] = 0u;
    if (verts4 && i < V) {
        const float* p = verts + (size_t)i * 3;
        verts4[i] = make_float4(p[0], p[1], p[2], 0.f);
    }
}

// ---- fused geometry + binning (round-6 measured-best structure) ----
__global__ __launch_bounds__(256) void fused_geom_bin_kernel(
    const float4* __restrict__ verts4,
    const int4*  __restrict__ idx4,
    const float* __restrict__ dens,
    float* __restrict__ out_area,
    float* __restrict__ out_alpha,
    uint2*       __restrict__ pairs,   // NB x BCAP
    unsigned*    __restrict__ gcnt,    // NB
    unsigned*    __restrict__ vd,      // overflow fallback target (zeroed)
    int T)
{
    __shared__ unsigned s_cnt[NB];
    __shared__ unsigned s_run[NB];
    __shared__ unsigned s_roff[NB];
    __shared__ unsigned s_wc[NB];
    __shared__ unsigned s_wsum[4];
    __shared__ uint2    stage[256 * RT * 4];   // 4096 pairs = 32 KB; total LDS ~36.2 KB

    int tid  = threadIdx.x;
    int lane = tid & 63;
    int wid  = tid >> 6;
    int base = blockIdx.x * (256 * RT * NR);

    // phase 1: count the block chunk (plain cached loads; rounds re-read L2-hot)
    s_cnt[tid] = 0u;
    __syncthreads();
    for (int k = 0; k < RT * NR; ++k) {
        int i = base + k * 256 + tid;
        if (i < T) {
            int4 q = idx4[i];
            atomicAdd(&s_cnt[(unsigned)q.x >> VSHIFT], 1u);
            atomicAdd(&s_cnt[(unsigned)q.y >> VSHIFT], 1u);
            atomicAdd(&s_cnt[(unsigned)q.z >> VSHIFT], 1u);
            atomicAdd(&s_cnt[(unsigned)q.w >> VSHIFT], 1u);
        }
    }
    __syncthreads();

    // phase 2: one global bump per (block, bucket)
    s_run[tid] = atomicAdd(&gcnt[tid], s_cnt[tid]);
    __syncthreads();

    // phase 3: rounds of RT tets/thread
    for (int r = 0; r < NR; ++r) {
        int4  q[RT];
        float dd[RT];
        bool  vl[RT];
#pragma unroll
        for (int k = 0; k < RT; ++k) {
            int i = base + (r * RT + k) * 256 + tid;
            vl[k] = (i < T);
            if (vl[k]) { q[k] = idx4[i]; dd[k] = dens[i]; }
        }

        // geometry: gathers + register compute + NT output stores
#pragma unroll
        for (int k = 0; k < RT; ++k) if (vl[k]) {
            int i = base + (r * RT + k) * 256 + tid;
            float4 v0 = verts4[q[k].x];
            float4 v1 = verts4[q[k].y];
            float4 v2 = verts4[q[k].z];
            float4 v3 = verts4[q[k].w];

            float e1x = v1.x - v0.x, e1y = v1.y - v0.y, e1z = v1.z - v0.z;
            float e2x = v2.x - v0.x, e2y = v2.y - v0.y, e2z = v2.z - v0.z;
            float e3x = v3.x - v0.x, e3y = v3.y - v0.y, e3z = v3.z - v0.z;

            float det = e1x * (e2y * e3z - e2z * e3y)
                      - e1y * (e2x * e3z - e2z * e3x)
                      + e1z * (e2x * e3y - e2y * e3x);
            __builtin_nontemporal_store(fabsf(det) * (1.0f / 6.0f), &out_area[i]);

            float q01 = e1x * e1x + e1y * e1y + e1z * e1z;
            float q02 = e2x * e2x + e2y * e2y + e2z * e2z;
            float q03 = e3x * e3x + e3y * e3y + e3z * e3z;
            float ax, ay, az;
            ax = v1.x - v2.x; ay = v1.y - v2.y; az = v1.z - v2.z;
            float q12 = ax * ax + ay * ay + az * az;
            ax = v1.x - v3.x; ay = v1.y - v3.y; az = v1.z - v3.z;
            float q13 = ax * ax + ay * ay + az * az;
            ax = v2.x - v3.x; ay = v2.y - v3.y; az = v2.z - v3.z;
            float q23 = ax * ax + ay * ay + az * az;

            float mn = fminf(fminf(fminf(q01, q02), fminf(q03, q12)), fminf(q13, q23));
            float el = sqrtf(mn);
            __builtin_nontemporal_store(1.0f - expf(-dd[k] * el), &out_alpha[i]);
        }

        // round histogram
        s_cnt[tid] = 0u;
        __syncthreads();
#pragma unroll
        for (int k = 0; k < RT; ++k) if (vl[k]) {
            atomicAdd(&s_cnt[(unsigned)q[k].x >> VSHIFT], 1u);
            atomicAdd(&s_cnt[(unsigned)q[k].y >> VSHIFT], 1u);
            atomicAdd(&s_cnt[(unsigned)q[k].z >> VSHIFT], 1u);
            atomicAdd(&s_cnt[(unsigned)q[k].w >> VSHIFT], 1u);
        }
        __syncthreads();

        // wave-shuffle exclusive scan (2 barriers, verified rounds 7/8)
        unsigned x = s_cnt[tid];
        unsigned incl = x;
#pragma unroll
        for (int s = 1; s < 64; s <<= 1) {
            unsigned t = __shfl_up(incl, s);
            if (lane >= s) incl += t;
        }
        if (lane == 63) s_wsum[wid] = incl;
        __syncthreads();
        unsigned pre = 0;
#pragma unroll
        for (int w = 0; w < 4; ++w) pre += (w < wid) ? s_wsum[w] : 0u;
        unsigned npairs = s_wsum[0] + s_wsum[1] + s_wsum[2] + s_wsum[3];
        s_roff[tid] = pre + incl - x;
        s_wc[tid]   = 0u;
        __syncthreads();

        // scatter round pairs into bucket-compacted staging
#pragma unroll
        for (int k = 0; k < RT; ++k) if (vl[k]) {
            unsigned db = __float_as_uint(dd[k]);
            unsigned vv[4] = { (unsigned)q[k].x, (unsigned)q[k].y,
                               (unsigned)q[k].z, (unsigned)q[k].w };
#pragma unroll
            for (int j = 0; j < 4; ++j) {
                unsigned b    = vv[j] >> VSHIFT;
                unsigned slot = s_roff[b] + atomicAdd(&s_wc[b], 1u);
                stage[slot] = make_uint2(vv[j], db);
            }
        }
        __syncthreads();

        // coalesced flush; NT stores: pairs are write-once, read much later --
        // keep them from evicting verts4/idx lines in L2.
        for (unsigned l = tid; l < npairs; l += 256) {
            uint2 e = stage[l];
            unsigned b  = e.x >> VSHIFT;
            unsigned rr = s_run[b] + (l - s_roff[b]);
            if (rr < BCAP) {
                nt_uint2 ev; ev.x = e.x; ev.y = e.y;
                __builtin_nontemporal_store(ev, (nt_uint2*)(pairs + (size_t)b * BCAP + rr));
            } else {
                atomicMax(vd + e.x, e.y); // astronomically rare; correct
            }
        }
        __syncthreads();

        // advance running bases (read by next round's flush; ordered by barriers)
        s_run[tid] += s_cnt[tid];
    }
}

// ---- per-bucket max in LDS: zero global atomics; vectorized pair reads ----
__global__ __launch_bounds__(1024) void bucket_max_kernel(
    const uint2*    __restrict__ pairs,
    const unsigned* __restrict__ gcnt,
    unsigned*       __restrict__ vd,
    int V)
{
    __shared__ unsigned tbl[1 << VSHIFT];
    int b   = blockIdx.x;
    int tid = threadIdx.x;

    for (int j = tid; j < (1 << VSHIFT); j += 1024) tbl[j] = 0u;
    __syncthreads();

    unsigned cnt = gcnt[b];
    if (cnt > BCAP) cnt = BCAP;
    const uint4* p4 = (const uint4*)(pairs + (size_t)b * BCAP);  // 16B-aligned (BCAP even)
    unsigned n2 = cnt >> 1;
    for (unsigned i = tid; i < n2; i += 1024) {
        uint4 e = p4[i];
        atomicMax(&tbl[e.x & BMASK], e.y);   // ds_max_u32: on-chip
        atomicMax(&tbl[e.z & BMASK], e.w);
    }
    if (tid == 0 && (cnt & 1u)) {
        uint2 e = pairs[(size_t)b * BCAP + cnt - 1];
        atomicMax(&tbl[e.x & BMASK], e.y);
    }
    __syncthreads();

    int vbase = b << VSHIFT;
    for (int j = tid; j < (1 << VSHIFT); j += 1024) {
        int v = vbase + j;
        if (v < V) {
            unsigned cur = vd[v];            // merge overflow-fallback atomics
            unsigned t   = tbl[j];
            vd[v] = cur > t ? cur : t;
        }
    }
}

// ---------------- tier-3: round-3 verified kernel (read-filtered atomics) ----------------
__global__ __launch_bounds__(256) void tet_kernel_filter(
    const float4* __restrict__ verts4,
    const int*   __restrict__ indices,
    const float* __restrict__ density,
    float* __restrict__ out_area,
    float* __restrict__ out_alpha,
    unsigned int* __restrict__ vd,
    int T)
{
    int i = blockIdx.x * blockDim.x + threadIdx.x;
    if (i >= T) return;

    nt_int4 idx = __builtin_nontemporal_load((const nt_int4*)indices + i);
    float d     = __builtin_nontemporal_load(&density[i]);
    unsigned int db = __float_as_uint(d);

    unsigned int c0 = vd[idx.x];
    unsigned int c1 = vd[idx.y];
    unsigned int c2 = vd[idx.z];
    unsigned int c3 = vd[idx.w];

    float4 v0 = verts4[idx.x];
    float4 v1 = verts4[idx.y];
    float4 v2 = verts4[idx.z];
    float4 v3 = verts4[idx.w];

    float e1x = v1.x - v0.x, e1y = v1.y - v0.y, e1z = v1.z - v0.z;
    float e2x = v2.x - v0.x, e2y = v2.y - v0.y, e2z = v2.z - v0.z;
    float e3x = v3.x - v0.x, e3y = v3.y - v0.y, e3z = v3.z - v0.z;

    float det = e1x * (e2y * e3z - e2z * e3y)
              - e1y * (e2x * e3z - e2z * e3x)
              + e1z * (e2x * e3y - e2y * e3x);
    __builtin_nontemporal_store(fabsf(det) * (1.0f / 6.0f), &out_area[i]);

    float q01 = e1x * e1x + e1y * e1y + e1z * e1z;
    float q02 = e2x * e2x + e2y * e2y + e2z * e2z;
    float q03 = e3x * e3x + e3y * e3y + e3z * e3z;
    float ax, ay, az;
    ax = v1.x - v2.x; ay = v1.y - v2.y; az = v1.z - v2.z;
    float q12 = ax * ax + ay * ay + az * az;
    ax = v1.x - v3.x; ay = v1.y - v3.y; az = v1.z - v3.z;
    float q13 = ax * ax + ay * ay + az * az;
    ax = v2.x - v3.x; ay = v2.y - v3.y; az = v2.z - v3.z;
    float q23 = ax * ax + ay * ay + az * az;

    float mn = fminf(fminf(fminf(q01, q02), fminf(q03, q12)), fminf(q13, q23));
    float el = sqrtf(mn);
    __builtin_nontemporal_store(1.0f - expf(-d * el), &out_alpha[i]);

    if (db > c0) atomicMax(vd + idx.x, db);
    if (db > c1) atomicMax(vd + idx.y, db);
    if (db > c2) atomicMax(vd + idx.z, db);
    if (db > c3) atomicMax(vd + idx.w, db);
}

// ---------------- tier-4: round-0 verified kernel ----------------
__global__ __launch_bounds__(256) void tet_kernel_fb(
    const float* __restrict__ verts,
    const int4*  __restrict__ indices,
    const float* __restrict__ density,
    float* __restrict__ out_area,
    float* __restrict__ out_alpha,
    unsigned int* __restrict__ vd,
    int T)
{
    int i = blockIdx.x * blockDim.x + threadIdx.x;
    if (i >= T) return;

    int4 idx = indices[i];
    float d = density[i];

    const float* p;
    p = verts + idx.x * 3; float v0x = p[0], v0y = p[1], v0z = p[2];
    p = verts + idx.y * 3; float v1x = p[0], v1y = p[1], v1z = p[2];
    p = verts + idx.z * 3; float v2x = p[0], v2y = p[1], v2z = p[2];
    p = verts + idx.w * 3; float v3x = p[0], v3y = p[1], v3z = p[2];

    float e1x = v1x - v0x, e1y = v1y - v0y, e1z = v1z - v0z;
    float e2x = v2x - v0x, e2y = v2y - v0y, e2z = v2z - v0z;
    float e3x = v3x - v0x, e3y = v3y - v0y, e3z = v3z - v0z;

    float det = e1x * (e2y * e3z - e2z * e3y)
              - e1y * (e2x * e3z - e2z * e3x)
              + e1z * (e2x * e3y - e2y * e3x);
    out_area[i] = fabsf(det) * (1.0f / 6.0f);

    float q01 = e1x * e1x + e1y * e1y + e1z * e1z;
    float q02 = e2x * e2x + e2y * e2y + e2z * e2z;
    float q03 = e3x * e3x + e3y * e3y + e3z * e3z;
    float ax, ay, az;
    ax = v1x - v2x; ay = v1y - v2y; az = v1z - v2z;
    float q12 = ax * ax + ay * ay + az * az;
    ax = v1x - v3x; ay = v1y - v3y; az = v1z - v3z;
    float q13 = ax * ax + ay * ay + az * az;
    ax = v2x - v3x; ay = v2y - v3y; az = v2z - v3z;
    float q23 = ax * ax + ay * ay + az * az;

    float mn = fminf(fminf(fminf(q01, q02), fminf(q03, q12)), fminf(q13, q23));
    float el = sqrtf(mn);
    out_alpha[i] = 1.0f - expf(-d * el);

    unsigned int db = __float_as_uint(d);
    atomicMax(vd + idx.x, db);
    atomicMax(vd + idx.y, db);
    atomicMax(vd + idx.z, db);
    atomicMax(vd + idx.w, db);
}

// ---------------- launch ----------------

extern "C" void kernel_launch(void* const* d_in, const int* in_sizes, int n_in,
                              void* d_out, int out_size, void* d_ws, size_t ws_size,
                              hipStream_t stream) {
    const float* verts   = (const float*)d_in[0];
    const int*   indices = (const int*)d_in[1];
    const float* density = (const float*)d_in[2];
    int T = in_sizes[2];        // 4,000,000 tets
    int V = in_sizes[0] / 3;    // 1,000,000 vertices

    float* out       = (float*)d_out;
    float* out_area  = out;
    float* out_alpha = out + (size_t)T;
    unsigned int* vd = (unsigned int*)(out + 2 * (size_t)T);

    const int block = 256;
    int n4 = V / 4;

    size_t pairsB = (size_t)NB * BCAP * sizeof(uint2);   // 128 MB
    size_t cntB   = (size_t)NB * sizeof(unsigned);
    size_t v4B    = (size_t)V * sizeof(float4);          // 16 MB

    double mean = 4.0 * (double)T / NB;
    bool capOK = (mean + 12.0 * __builtin_sqrt(mean) <= (double)BCAP);
    bool fastOK = (V % 4 == 0) && (V <= (NB << VSHIFT)) && capOK && d_ws;

    int tetsPerBlock = block * RT * NR;   // 4096
    int nbAct = (V + (1 << VSHIFT) - 1) >> VSHIFT;

    if (fastOK && ws_size >= pairsB + cntB + v4B) {
        uint2*    pairs  = (uint2*)d_ws;
        unsigned* gcnt   = (unsigned*)((char*)d_ws + pairsB);
        float4*   verts4 = (float4*)((char*)d_ws + pairsB + ((cntB + 255) & ~(size_t)255));

        int setupN = (V > n4 ? V : n4);
        setup_kernel<<<(setupN + block - 1) / block, block, 0, stream>>>(
            (uint4*)vd, n4, gcnt, verts, verts4, V);

        fused_geom_bin_kernel<<<(T + tetsPerBlock - 1) / tetsPerBlock, block, 0, stream>>>(
            verts4, (const int4*)indices, density, out_area, out_alpha, pairs, gcnt, vd, T);

        bucket_max_kernel<<<nbAct, 1024, 0, stream>>>(pairs, gcnt, vd, V);
    } else if (d_ws && ws_size >= v4B && (V % 4) == 0) {
        // tier-3: round-3 verified path
        float4* verts4 = (float4*)d_ws;
        int setupN = (V > n4 ? V : n4);
        setup_kernel<<<(setupN + block - 1) / block, block, 0, stream>>>(
            (uint4*)vd, n4, nullptr, verts, verts4, V);
        tet_kernel_filter<<<(T + block - 1) / block, block, 0, stream>>>(
            verts4, indices, density, out_area, out_alpha, vd, T);
    } else {
        // tier-4: round-0 verified path
        setup_kernel<<<(n4 + block - 1) / block, block, 0, stream>>>(
            (uint4*)vd, n4, nullptr, nullptr, nullptr, 0);
        tet_kernel_fb<<<(T + block - 1) / block, block, 0, stream>>>(
            verts, (const int4*)indices, density, out_area, out_alpha, vd, T);
    }
}

// Round 10
// 412.911 us; speedup vs baseline: 1.0862x; 1.0512x over previous
//
#include <hip/hip_runtime.h>

// clang-native vector types: __builtin_nontemporal_* rejects HIP_vector_type wrappers.
typedef int nt_int4 __attribute__((ext_vector_type(4)));

#define NB     256        // vertex buckets (== bin block threads)
#define VSHIFT 12         // 4096 verts per bucket -> 16 KB LDS table
#define BMASK  ((1 << VSHIFT) - 1)
#define BCAP   65536      // pairs per bucket capacity (mean 62.5K + 12 sigma)
#define RT     4          // tets per thread per round (16 gathers in flight: measured best)
#define NR     4          // rounds -> 4096 tets per block (round-6/9 best config)

// Packed pair: (v_local:12 << 20) | (density_bits >> 12).
// Truncating a positive float's low 12 mantissa bits is MONOTONE, so
// max(packed) selects the max density; restored value w<<12 errs <= 2^-12
// (tolerance is 2^-7). Halves pair bytes: 128 MB -> 64 MB each way.

// Fused setup: zero vd region (harness poisons d_out), zero bucket counters,
// pad 12B-strided verts to 16B float4.
__global__ __launch_bounds__(256) void setup_kernel(uint4* __restrict__ vd4, int n4,
                                                    unsigned* __restrict__ gcnt,
                                                    const float* __restrict__ verts,
                                                    float4* __restrict__ verts4, int V) {
    int i = blockIdx.x * blockDim.x + threadIdx.x;
    if (i < n4) vd4[i] = make_uint4(0u, 0u, 0u, 0u);
    if (gcnt && i < NB) gcnt[i] = 0u;
    if (verts4 && i < V) {
        const float* p = verts + (size_t)i * 3;
        verts4[i] = make_float4(p[0], p[1], p[2], 0.f);
    }
}

// ---- fused geometry + binning (round-9 structure, 4B packed pair flush) ----
__global__ __launch_bounds__(256) void fused_geom_bin_kernel(
    const float4* __restrict__ verts4,
    const int4*  __restrict__ idx4,
    const float* __restrict__ dens,
    float* __restrict__ out_area,
    float* __restrict__ out_alpha,
    unsigned*    __restrict__ pairs,   // NB x BCAP packed u32
    unsigned*    __restrict__ gcnt,    // NB
    unsigned*    __restrict__ vd,      // overflow fallback target (zeroed)
    int T)
{
    __shared__ unsigned s_cnt[NB];
    __shared__ unsigned s_run[NB];
    __shared__ unsigned s_roff[NB];
    __shared__ unsigned s_wc[NB];
    __shared__ unsigned s_wsum[4];
    __shared__ uint2    stage[256 * RT * 4];   // 4096 pairs = 32 KB; total LDS ~37 KB

    int tid  = threadIdx.x;
    int lane = tid & 63;
    int wid  = tid >> 6;
    int base = blockIdx.x * (256 * RT * NR);

    // phase 1: count the block chunk (plain cached loads; rounds re-read L2-hot)
    s_cnt[tid] = 0u;
    __syncthreads();
    for (int k = 0; k < RT * NR; ++k) {
        int i = base + k * 256 + tid;
        if (i < T) {
            int4 q = idx4[i];
            atomicAdd(&s_cnt[(unsigned)q.x >> VSHIFT], 1u);
            atomicAdd(&s_cnt[(unsigned)q.y >> VSHIFT], 1u);
            atomicAdd(&s_cnt[(unsigned)q.z >> VSHIFT], 1u);
            atomicAdd(&s_cnt[(unsigned)q.w >> VSHIFT], 1u);
        }
    }
    __syncthreads();

    // phase 2: one global bump per (block, bucket)
    s_run[tid] = atomicAdd(&gcnt[tid], s_cnt[tid]);
    __syncthreads();

    // phase 3: rounds of RT tets/thread
    for (int r = 0; r < NR; ++r) {
        int4  q[RT];
        float dd[RT];
        bool  vl[RT];
#pragma unroll
        for (int k = 0; k < RT; ++k) {
            int i = base + (r * RT + k) * 256 + tid;
            vl[k] = (i < T);
            if (vl[k]) { q[k] = idx4[i]; dd[k] = dens[i]; }
        }

        // geometry: gathers + register compute + NT output stores
#pragma unroll
        for (int k = 0; k < RT; ++k) if (vl[k]) {
            int i = base + (r * RT + k) * 256 + tid;
            float4 v0 = verts4[q[k].x];
            float4 v1 = verts4[q[k].y];
            float4 v2 = verts4[q[k].z];
            float4 v3 = verts4[q[k].w];

            float e1x = v1.x - v0.x, e1y = v1.y - v0.y, e1z = v1.z - v0.z;
            float e2x = v2.x - v0.x, e2y = v2.y - v0.y, e2z = v2.z - v0.z;
            float e3x = v3.x - v0.x, e3y = v3.y - v0.y, e3z = v3.z - v0.z;

            float det = e1x * (e2y * e3z - e2z * e3y)
                      - e1y * (e2x * e3z - e2z * e3x)
                      + e1z * (e2x * e3y - e2y * e3x);
            __builtin_nontemporal_store(fabsf(det) * (1.0f / 6.0f), &out_area[i]);

            float q01 = e1x * e1x + e1y * e1y + e1z * e1z;
            float q02 = e2x * e2x + e2y * e2y + e2z * e2z;
            float q03 = e3x * e3x + e3y * e3y + e3z * e3z;
            float ax, ay, az;
            ax = v1.x - v2.x; ay = v1.y - v2.y; az = v1.z - v2.z;
            float q12 = ax * ax + ay * ay + az * az;
            ax = v1.x - v3.x; ay = v1.y - v3.y; az = v1.z - v3.z;
            float q13 = ax * ax + ay * ay + az * az;
            ax = v2.x - v3.x; ay = v2.y - v3.y; az = v2.z - v3.z;
            float q23 = ax * ax + ay * ay + az * az;

            float mn = fminf(fminf(fminf(q01, q02), fminf(q03, q12)), fminf(q13, q23));
            float el = sqrtf(mn);
            __builtin_nontemporal_store(1.0f - expf(-dd[k] * el), &out_alpha[i]);
        }

        // round histogram
        s_cnt[tid] = 0u;
        __syncthreads();
#pragma unroll
        for (int k = 0; k < RT; ++k) if (vl[k]) {
            atomicAdd(&s_cnt[(unsigned)q[k].x >> VSHIFT], 1u);
            atomicAdd(&s_cnt[(unsigned)q[k].y >> VSHIFT], 1u);
            atomicAdd(&s_cnt[(unsigned)q[k].z >> VSHIFT], 1u);
            atomicAdd(&s_cnt[(unsigned)q[k].w >> VSHIFT], 1u);
        }
        __syncthreads();

        // wave-shuffle exclusive scan (2 barriers)
        unsigned x = s_cnt[tid];
        unsigned incl = x;
#pragma unroll
        for (int s = 1; s < 64; s <<= 1) {
            unsigned t = __shfl_up(incl, s);
            if (lane >= s) incl += t;
        }
        if (lane == 63) s_wsum[wid] = incl;
        __syncthreads();
        unsigned pre = 0;
#pragma unroll
        for (int w = 0; w < 4; ++w) pre += (w < wid) ? s_wsum[w] : 0u;
        unsigned npairs = s_wsum[0] + s_wsum[1] + s_wsum[2] + s_wsum[3];
        s_roff[tid] = pre + incl - x;
        s_wc[tid]   = 0u;
        __syncthreads();

        // scatter round pairs into bucket-compacted staging
#pragma unroll
        for (int k = 0; k < RT; ++k) if (vl[k]) {
            unsigned db = __float_as_uint(dd[k]);
            unsigned vv[4] = { (unsigned)q[k].x, (unsigned)q[k].y,
                               (unsigned)q[k].z, (unsigned)q[k].w };
#pragma unroll
            for (int j = 0; j < 4; ++j) {
                unsigned b    = vv[j] >> VSHIFT;
                unsigned slot = s_roff[b] + atomicAdd(&s_wc[b], 1u);
                stage[slot] = make_uint2(vv[j], db);
            }
        }
        __syncthreads();

        // coalesced flush of 4B packed pairs (NT: write-once, read much later)
        for (unsigned l = tid; l < npairs; l += 256) {
            uint2 e = stage[l];
            unsigned b  = e.x >> VSHIFT;
            unsigned rr = s_run[b] + (l - s_roff[b]);
            if (rr < BCAP) {
                unsigned w = ((e.x & BMASK) << 20) | (e.y >> 12);
                __builtin_nontemporal_store(w, pairs + (size_t)b * BCAP + rr);
            } else {
                atomicMax(vd + e.x, e.y); // astronomically rare; full precision
            }
        }
        __syncthreads();

        // advance running bases (read by next round's flush; ordered by barriers)
        s_run[tid] += s_cnt[tid];
    }
}

// ---- per-bucket max in LDS: zero global atomics; uint4 = 4 packed pairs/read ----
__global__ __launch_bounds__(1024) void bucket_max_kernel(
    const unsigned* __restrict__ pairs,
    const unsigned* __restrict__ gcnt,
    unsigned*       __restrict__ vd,
    int V)
{
    __shared__ unsigned tbl[1 << VSHIFT];
    int b   = blockIdx.x;
    int tid = threadIdx.x;

    for (int j = tid; j < (1 << VSHIFT); j += 1024) tbl[j] = 0u;
    __syncthreads();

    unsigned cnt = gcnt[b];
    if (cnt > BCAP) cnt = BCAP;
    const unsigned* p = pairs + (size_t)b * BCAP;
    const uint4* p4 = (const uint4*)p;          // 16B-aligned: BCAP*4 % 16 == 0
    unsigned n4c = cnt >> 2;
    for (unsigned i = tid; i < n4c; i += 1024) {
        uint4 e = p4[i];
        atomicMax(&tbl[e.x >> 20], e.x << 12);  // ds_max_u32: on-chip
        atomicMax(&tbl[e.y >> 20], e.y << 12);
        atomicMax(&tbl[e.z >> 20], e.z << 12);
        atomicMax(&tbl[e.w >> 20], e.w << 12);
    }
    if (tid < (cnt & 3u)) {                      // tail (<=3 entries)
        unsigned w = p[(cnt & ~3u) + tid];
        atomicMax(&tbl[w >> 20], w << 12);
    }
    __syncthreads();

    int vbase = b << VSHIFT;
    for (int j = tid; j < (1 << VSHIFT); j += 1024) {
        int v = vbase + j;
        if (v < V) {
            unsigned cur = vd[v];            // merge overflow-fallback atomics
            unsigned t   = tbl[j];
            vd[v] = cur > t ? cur : t;
        }
    }
}

// ---------------- tier-3: round-3 verified kernel (read-filtered atomics) ----------------
__global__ __launch_bounds__(256) void tet_kernel_filter(
    const float4* __restrict__ verts4,
    const int*   __restrict__ indices,
    const float* __restrict__ density,
    float* __restrict__ out_area,
    float* __restrict__ out_alpha,
    unsigned int* __restrict__ vd,
    int T)
{
    int i = blockIdx.x * blockDim.x + threadIdx.x;
    if (i >= T) return;

    nt_int4 idx = __builtin_nontemporal_load((const nt_int4*)indices + i);
    float d     = __builtin_nontemporal_load(&density[i]);
    unsigned int db = __float_as_uint(d);

    unsigned int c0 = vd[idx.x];
    unsigned int c1 = vd[idx.y];
    unsigned int c2 = vd[idx.z];
    unsigned int c3 = vd[idx.w];

    float4 v0 = verts4[idx.x];
    float4 v1 = verts4[idx.y];
    float4 v2 = verts4[idx.z];
    float4 v3 = verts4[idx.w];

    float e1x = v1.x - v0.x, e1y = v1.y - v0.y, e1z = v1.z - v0.z;
    float e2x = v2.x - v0.x, e2y = v2.y - v0.y, e2z = v2.z - v0.z;
    float e3x = v3.x - v0.x, e3y = v3.y - v0.y, e3z = v3.z - v0.z;

    float det = e1x * (e2y * e3z - e2z * e3y)
              - e1y * (e2x * e3z - e2z * e3x)
              + e1z * (e2x * e3y - e2y * e3x);
    __builtin_nontemporal_store(fabsf(det) * (1.0f / 6.0f), &out_area[i]);

    float q01 = e1x * e1x + e1y * e1y + e1z * e1z;
    float q02 = e2x * e2x + e2y * e2y + e2z * e2z;
    float q03 = e3x * e3x + e3y * e3y + e3z * e3z;
    float ax, ay, az;
    ax = v1.x - v2.x; ay = v1.y - v2.y; az = v1.z - v2.z;
    float q12 = ax * ax + ay * ay + az * az;
    ax = v1.x - v3.x; ay = v1.y - v3.y; az = v1.z - v3.z;
    float q13 = ax * ax + ay * ay + az * az;
    ax = v2.x - v3.x; ay = v2.y - v3.y; az = v2.z - v3.z;
    float q23 = ax * ax + ay * ay + az * az;

    float mn = fminf(fminf(fminf(q01, q02), fminf(q03, q12)), fminf(q13, q23));
    float el = sqrtf(mn);
    __builtin_nontemporal_store(1.0f - expf(-d * el), &out_alpha[i]);

    if (db > c0) atomicMax(vd + idx.x, db);
    if (db > c1) atomicMax(vd + idx.y, db);
    if (db > c2) atomicMax(vd + idx.z, db);
    if (db > c3) atomicMax(vd + idx.w, db);
}

// ---------------- tier-4: round-0 verified kernel ----------------
__global__ __launch_bounds__(256) void tet_kernel_fb(
    const float* __restrict__ verts,
    const int4*  __restrict__ indices,
    const float* __restrict__ density,
    float* __restrict__ out_area,
    float* __restrict__ out_alpha,
    unsigned int* __restrict__ vd,
    int T)
{
    int i = blockIdx.x * blockDim.x + threadIdx.x;
    if (i >= T) return;

    int4 idx = indices[i];
    float d = density[i];

    const float* p;
    p = verts + idx.x * 3; float v0x = p[0], v0y = p[1], v0z = p[2];
    p = verts + idx.y * 3; float v1x = p[0], v1y = p[1], v1z = p[2];
    p = verts + idx.z * 3; float v2x = p[0], v2y = p[1], v2z = p[2];
    p = verts + idx.w * 3; float v3x = p[0], v3y = p[1], v3z = p[2];

    float e1x = v1x - v0x, e1y = v1y - v0y, e1z = v1z - v0z;
    float e2x = v2x - v0x, e2y = v2y - v0y, e2z = v2z - v0z;
    float e3x = v3x - v0x, e3y = v3y - v0y, e3z = v3z - v0z;

    float det = e1x * (e2y * e3z - e2z * e3y)
              - e1y * (e2x * e3z - e2z * e3x)
              + e1z * (e2x * e3y - e2y * e3x);
    out_area[i] = fabsf(det) * (1.0f / 6.0f);

    float q01 = e1x * e1x + e1y * e1y + e1z * e1z;
    float q02 = e2x * e2x + e2y * e2y + e2z * e2z;
    float q03 = e3x * e3x + e3y * e3y + e3z * e3z;
    float ax, ay, az;
    ax = v1x - v2x; ay = v1y - v2y; az = v1z - v2z;
    float q12 = ax * ax + ay * ay + az * az;
    ax = v1x - v3x; ay = v1y - v3y; az = v1z - v3z;
    float q13 = ax * ax + ay * ay + az * az;
    ax = v2x - v3x; ay = v2y - v3y; az = v2z - v3z;
    float q23 = ax * ax + ay * ay + az * az;

    float mn = fminf(fminf(fminf(q01, q02), fminf(q03, q12)), fminf(q13, q23));
    float el = sqrtf(mn);
    out_alpha[i] = 1.0f - expf(-d * el);

    unsigned int db = __float_as_uint(d);
    atomicMax(vd + idx.x, db);
    atomicMax(vd + idx.y, db);
    atomicMax(vd + idx.z, db);
    atomicMax(vd + idx.w, db);
}

// ---------------- launch ----------------

extern "C" void kernel_launch(void* const* d_in, const int* in_sizes, int n_in,
                              void* d_out, int out_size, void* d_ws, size_t ws_size,
                              hipStream_t stream) {
    const float* verts   = (const float*)d_in[0];
    const int*   indices = (const int*)d_in[1];
    const float* density = (const float*)d_in[2];
    int T = in_sizes[2];        // 4,000,000 tets
    int V = in_sizes[0] / 3;    // 1,000,000 vertices

    float* out       = (float*)d_out;
    float* out_area  = out;
    float* out_alpha = out + (size_t)T;
    unsigned int* vd = (unsigned int*)(out + 2 * (size_t)T);

    const int block = 256;
    int n4 = V / 4;

    size_t pairsB = (size_t)NB * BCAP * sizeof(unsigned);  // 64 MB (packed)
    size_t cntB   = (size_t)NB * sizeof(unsigned);
    size_t v4B    = (size_t)V * sizeof(float4);            // 16 MB

    double mean = 4.0 * (double)T / NB;
    bool capOK = (mean + 12.0 * __builtin_sqrt(mean) <= (double)BCAP);
    bool fastOK = (V % 4 == 0) && (V <= (NB << VSHIFT)) && capOK && d_ws;

    int tetsPerBlock = block * RT * NR;   // 4096
    int nbAct = (V + (1 << VSHIFT) - 1) >> VSHIFT;

    if (fastOK && ws_size >= pairsB + cntB + v4B) {
        unsigned* pairs  = (unsigned*)d_ws;
        unsigned* gcnt   = (unsigned*)((char*)d_ws + pairsB);
        float4*   verts4 = (float4*)((char*)d_ws + pairsB + ((cntB + 255) & ~(size_t)255));

        int setupN = (V > n4 ? V : n4);
        setup_kernel<<<(setupN + block - 1) / block, block, 0, stream>>>(
            (uint4*)vd, n4, gcnt, verts, verts4, V);

        fused_geom_bin_kernel<<<(T + tetsPerBlock - 1) / tetsPerBlock, block, 0, stream>>>(
            verts4, (const int4*)indices, density, out_area, out_alpha, pairs, gcnt, vd, T);

        bucket_max_kernel<<<nbAct, 1024, 0, stream>>>(pairs, gcnt, vd, V);
    } else if (d_ws && ws_size >= v4B && (V % 4) == 0) {
        // tier-3: round-3 verified path
        float4* verts4 = (float4*)d_ws;
        int setupN = (V > n4 ? V : n4);
        setup_kernel<<<(setupN + block - 1) / block, block, 0, stream>>>(
            (uint4*)vd, n4, nullptr, verts, verts4, V);
        tet_kernel_filter<<<(T + block - 1) / block, block, 0, stream>>>(
            verts4, indices, density, out_area, out_alpha, vd, T);
    } else {
        // tier-4: round-0 verified path
        setup_kernel<<<(n4 + block - 1) / block, block, 0, stream>>>(
            (uint4*)vd, n4, nullptr, nullptr, nullptr, 0);
        tet_kernel_fb<<<(T + block - 1) / block, block, 0, stream>>>(
            verts, (const int4*)indices, density, out_area, out_alpha, vd, T);
    }
}

// Round 11
// 401.903 us; speedup vs baseline: 1.1160x; 1.0274x over previous
//
#include <hip/hip_runtime.h>

// clang-native vector types: __builtin_nontemporal_* rejects HIP_vector_type wrappers.
typedef int nt_int4 __attribute__((ext_vector_type(4)));

#define NB     256        // vertex buckets (== bin block threads)
#define VSHIFT 12         // 4096 verts per bucket -> 16 KB LDS table
#define BMASK  ((1 << VSHIFT) - 1)
#define BCAP   65536      // pairs per bucket capacity
#define RT     4          // tets per thread per round (16 gathers in flight: measured best)
#define NR     4          // rounds -> 4096 tets per block
#define GPAD   16         // gcnt stride (u32): one counter per 64B line, no RMW line contention

// Packed pair: (v_local:12 << 20) | (density_bits >> 12).
// Truncating a positive float's low 12 mantissa bits is MONOTONE, so
// max(packed) selects the max density; restored value w<<12 errs <= 2^-12
// (tolerance is 2^-7). Verified round 10 (absmax unchanged).

// Fused setup: zero vd region (harness poisons d_out), zero padded bucket
// counters, pad 12B-strided verts to 16B float4.
__global__ __launch_bounds__(256) void setup_kernel(uint4* __restrict__ vd4, int n4,
                                                    unsigned* __restrict__ gcnt,
                                                    const float* __restrict__ verts,
                                                    float4* __restrict__ verts4, int V) {
    int i = blockIdx.x * blockDim.x + threadIdx.x;
    if (i < n4) vd4[i] = make_uint4(0u, 0u, 0u, 0u);
    if (gcnt && i < NB * GPAD) gcnt[i] = 0u;
    if (verts4 && i < V) {
        const float* p = verts + (size_t)i * 3;
        verts4[i] = make_float4(p[0], p[1], p[2], 0.f);
    }
}

// ---- fused geometry + binning: per-round allocation (phase-1 pre-count removed;
// idx read exactly once; first gathers issue immediately) ----
__global__ __launch_bounds__(256) void fused_geom_bin_kernel(
    const float4* __restrict__ verts4,
    const int4*  __restrict__ idx4,
    const float* __restrict__ dens,
    float* __restrict__ out_area,
    float* __restrict__ out_alpha,
    unsigned*    __restrict__ pairs,   // NB x BCAP packed u32
    unsigned*    __restrict__ gcnt,    // NB x GPAD (line-padded)
    unsigned*    __restrict__ vd,      // overflow fallback target (zeroed)
    int T)
{
    __shared__ unsigned s_cnt[NB];
    __shared__ unsigned s_base[NB];
    __shared__ unsigned s_roff[NB];
    __shared__ unsigned s_wc[NB];
    __shared__ unsigned s_wsum[4];
    __shared__ uint2    stage[256 * RT * 4];   // 4096 pairs = 32 KB; total LDS ~36 KB

    int tid  = threadIdx.x;
    int lane = tid & 63;
    int wid  = tid >> 6;
    int base = blockIdx.x * (256 * RT * NR);

    for (int r = 0; r < NR; ++r) {
        int4  q[RT];
        float dd[RT];
        bool  vl[RT];
#pragma unroll
        for (int k = 0; k < RT; ++k) {
            int i = base + (r * RT + k) * 256 + tid;
            vl[k] = (i < T);
            if (vl[k]) { q[k] = idx4[i]; dd[k] = dens[i]; }
        }

        // geometry: gathers + register compute + NT output stores
#pragma unroll
        for (int k = 0; k < RT; ++k) if (vl[k]) {
            int i = base + (r * RT + k) * 256 + tid;
            float4 v0 = verts4[q[k].x];
            float4 v1 = verts4[q[k].y];
            float4 v2 = verts4[q[k].z];
            float4 v3 = verts4[q[k].w];

            float e1x = v1.x - v0.x, e1y = v1.y - v0.y, e1z = v1.z - v0.z;
            float e2x = v2.x - v0.x, e2y = v2.y - v0.y, e2z = v2.z - v0.z;
            float e3x = v3.x - v0.x, e3y = v3.y - v0.y, e3z = v3.z - v0.z;

            float det = e1x * (e2y * e3z - e2z * e3y)
                      - e1y * (e2x * e3z - e2z * e3x)
                      + e1z * (e2x * e3y - e2y * e3x);
            __builtin_nontemporal_store(fabsf(det) * (1.0f / 6.0f), &out_area[i]);

            float q01 = e1x * e1x + e1y * e1y + e1z * e1z;
            float q02 = e2x * e2x + e2y * e2y + e2z * e2z;
            float q03 = e3x * e3x + e3y * e3y + e3z * e3z;
            float ax, ay, az;
            ax = v1.x - v2.x; ay = v1.y - v2.y; az = v1.z - v2.z;
            float q12 = ax * ax + ay * ay + az * az;
            ax = v1.x - v3.x; ay = v1.y - v3.y; az = v1.z - v3.z;
            float q13 = ax * ax + ay * ay + az * az;
            ax = v2.x - v3.x; ay = v2.y - v3.y; az = v2.z - v3.z;
            float q23 = ax * ax + ay * ay + az * az;

            float mn = fminf(fminf(fminf(q01, q02), fminf(q03, q12)), fminf(q13, q23));
            float el = sqrtf(mn);
            __builtin_nontemporal_store(1.0f - expf(-dd[k] * el), &out_alpha[i]);
        }

        // round histogram
        s_cnt[tid] = 0u;
        __syncthreads();
#pragma unroll
        for (int k = 0; k < RT; ++k) if (vl[k]) {
            atomicAdd(&s_cnt[(unsigned)q[k].x >> VSHIFT], 1u);
            atomicAdd(&s_cnt[(unsigned)q[k].y >> VSHIFT], 1u);
            atomicAdd(&s_cnt[(unsigned)q[k].z >> VSHIFT], 1u);
            atomicAdd(&s_cnt[(unsigned)q[k].w >> VSHIFT], 1u);
        }
        __syncthreads();

        // wave-shuffle exclusive scan (2 barriers)
        unsigned x = s_cnt[tid];
        unsigned incl = x;
#pragma unroll
        for (int s = 1; s < 64; s <<= 1) {
            unsigned t = __shfl_up(incl, s);
            if (lane >= s) incl += t;
        }
        if (lane == 63) s_wsum[wid] = incl;
        __syncthreads();
        unsigned pre = 0;
#pragma unroll
        for (int w = 0; w < 4; ++w) pre += (w < wid) ? s_wsum[w] : 0u;
        unsigned npairs = s_wsum[0] + s_wsum[1] + s_wsum[2] + s_wsum[3];
        s_roff[tid] = pre + incl - x;
        s_wc[tid]   = 0u;
        // per-round global segment allocation (line-padded counter: no contention)
        s_base[tid] = atomicAdd(&gcnt[tid * GPAD], x);
        __syncthreads();

        // scatter round pairs into bucket-compacted staging
#pragma unroll
        for (int k = 0; k < RT; ++k) if (vl[k]) {
            unsigned db = __float_as_uint(dd[k]);
            unsigned vv[4] = { (unsigned)q[k].x, (unsigned)q[k].y,
                               (unsigned)q[k].z, (unsigned)q[k].w };
#pragma unroll
            for (int j = 0; j < 4; ++j) {
                unsigned b    = vv[j] >> VSHIFT;
                unsigned slot = s_roff[b] + atomicAdd(&s_wc[b], 1u);
                stage[slot] = make_uint2(vv[j], db);
            }
        }
        __syncthreads();

        // coalesced flush of 4B packed pairs (NT: write-once, read much later)
        for (unsigned l = tid; l < npairs; l += 256) {
            uint2 e = stage[l];
            unsigned b  = e.x >> VSHIFT;
            unsigned rr = s_base[b] + (l - s_roff[b]);
            if (rr < BCAP) {
                unsigned w = ((e.x & BMASK) << 20) | (e.y >> 12);
                __builtin_nontemporal_store(w, pairs + (size_t)b * BCAP + rr);
            } else {
                atomicMax(vd + e.x, e.y); // astronomically rare; full precision
            }
        }
        __syncthreads();
    }
}

// ---- per-bucket max in LDS: zero global atomics; uint4 = 4 packed pairs/read ----
__global__ __launch_bounds__(1024) void bucket_max_kernel(
    const unsigned* __restrict__ pairs,
    const unsigned* __restrict__ gcnt,   // NB x GPAD
    unsigned*       __restrict__ vd,
    int V)
{
    __shared__ unsigned tbl[1 << VSHIFT];
    int b   = blockIdx.x;
    int tid = threadIdx.x;

    for (int j = tid; j < (1 << VSHIFT); j += 1024) tbl[j] = 0u;
    __syncthreads();

    unsigned cnt = gcnt[b * GPAD];
    if (cnt > BCAP) cnt = BCAP;
    const unsigned* p = pairs + (size_t)b * BCAP;
    const uint4* p4 = (const uint4*)p;          // 16B-aligned: BCAP*4 % 16 == 0
    unsigned n4c = cnt >> 2;
    for (unsigned i = tid; i < n4c; i += 1024) {
        uint4 e = p4[i];
        atomicMax(&tbl[e.x >> 20], e.x << 12);  // ds_max_u32: on-chip
        atomicMax(&tbl[e.y >> 20], e.y << 12);
        atomicMax(&tbl[e.z >> 20], e.z << 12);
        atomicMax(&tbl[e.w >> 20], e.w << 12);
    }
    if (tid < (cnt & 3u)) {                      // tail (<=3 entries)
        unsigned w = p[(cnt & ~3u) + tid];
        atomicMax(&tbl[w >> 20], w << 12);
    }
    __syncthreads();

    int vbase = b << VSHIFT;
    for (int j = tid; j < (1 << VSHIFT); j += 1024) {
        int v = vbase + j;
        if (v < V) {
            unsigned cur = vd[v];            // merge overflow-fallback atomics
            unsigned t   = tbl[j];
            vd[v] = cur > t ? cur : t;
        }
    }
}

// ---------------- tier-3: round-3 verified kernel (read-filtered atomics) ----------------
__global__ __launch_bounds__(256) void tet_kernel_filter(
    const float4* __restrict__ verts4,
    const int*   __restrict__ indices,
    const float* __restrict__ density,
    float* __restrict__ out_area,
    float* __restrict__ out_alpha,
    unsigned int* __restrict__ vd,
    int T)
{
    int i = blockIdx.x * blockDim.x + threadIdx.x;
    if (i >= T) return;

    nt_int4 idx = __builtin_nontemporal_load((const nt_int4*)indices + i);
    float d     = __builtin_nontemporal_load(&density[i]);
    unsigned int db = __float_as_uint(d);

    unsigned int c0 = vd[idx.x];
    unsigned int c1 = vd[idx.y];
    unsigned int c2 = vd[idx.z];
    unsigned int c3 = vd[idx.w];

    float4 v0 = verts4[idx.x];
    float4 v1 = verts4[idx.y];
    float4 v2 = verts4[idx.z];
    float4 v3 = verts4[idx.w];

    float e1x = v1.x - v0.x, e1y = v1.y - v0.y, e1z = v1.z - v0.z;
    float e2x = v2.x - v0.x, e2y = v2.y - v0.y, e2z = v2.z - v0.z;
    float e3x = v3.x - v0.x, e3y = v3.y - v0.y, e3z = v3.z - v0.z;

    float det = e1x * (e2y * e3z - e2z * e3y)
              - e1y * (e2x * e3z - e2z * e3x)
              + e1z * (e2x * e3y - e2y * e3x);
    __builtin_nontemporal_store(fabsf(det) * (1.0f / 6.0f), &out_area[i]);

    float q01 = e1x * e1x + e1y * e1y + e1z * e1z;
    float q02 = e2x * e2x + e2y * e2y + e2z * e2z;
    float q03 = e3x * e3x + e3y * e3y + e3z * e3z;
    float ax, ay, az;
    ax = v1.x - v2.x; ay = v1.y - v2.y; az = v1.z - v2.z;
    float q12 = ax * ax + ay * ay + az * az;
    ax = v1.x - v3.x; ay = v1.y - v3.y; az = v1.z - v3.z;
    float q13 = ax * ax + ay * ay + az * az;
    ax = v2.x - v3.x; ay = v2.y - v3.y; az = v2.z - v3.z;
    float q23 = ax * ax + ay * ay + az * az;

    float mn = fminf(fminf(fminf(q01, q02), fminf(q03, q12)), fminf(q13, q23));
    float el = sqrtf(mn);
    __builtin_nontemporal_store(1.0f - expf(-d * el), &out_alpha[i]);

    if (db > c0) atomicMax(vd + idx.x, db);
    if (db > c1) atomicMax(vd + idx.y, db);
    if (db > c2) atomicMax(vd + idx.z, db);
    if (db > c3) atomicMax(vd + idx.w, db);
}

// ---------------- tier-4: round-0 verified kernel ----------------
__global__ __launch_bounds__(256) void tet_kernel_fb(
    const float* __restrict__ verts,
    const int4*  __restrict__ indices,
    const float* __restrict__ density,
    float* __restrict__ out_area,
    float* __restrict__ out_alpha,
    unsigned int* __restrict__ vd,
    int T)
{
    int i = blockIdx.x * blockDim.x + threadIdx.x;
    if (i >= T) return;

    int4 idx = indices[i];
    float d = density[i];

    const float* p;
    p = verts + idx.x * 3; float v0x = p[0], v0y = p[1], v0z = p[2];
    p = verts + idx.y * 3; float v1x = p[0], v1y = p[1], v1z = p[2];
    p = verts + idx.z * 3; float v2x = p[0], v2y = p[1], v2z = p[2];
    p = verts + idx.w * 3; float v3x = p[0], v3y = p[1], v3z = p[2];

    float e1x = v1x - v0x, e1y = v1y - v0y, e1z = v1z - v0z;
    float e2x = v2x - v0x, e2y = v2y - v0y, e2z = v2z - v0z;
    float e3x = v3x - v0x, e3y = v3y - v0y, e3z = v3z - v0z;

    float det = e1x * (e2y * e3z - e2z * e3y)
              - e1y * (e2x * e3z - e2z * e3x)
              + e1z * (e2x * e3y - e2y * e3x);
    out_area[i] = fabsf(det) * (1.0f / 6.0f);

    float q01 = e1x * e1x + e1y * e1y + e1z * e1z;
    float q02 = e2x * e2x + e2y * e2y + e2z * e2z;
    float q03 = e3x * e3x + e3y * e3y + e3z * e3z;
    float ax, ay, az;
    ax = v1x - v2x; ay = v1y - v2y; az = v1z - v2z;
    float q12 = ax * ax + ay * ay + az * az;
    ax = v1x - v3x; ay = v1y - v3y; az = v1z - v3z;
    float q13 = ax * ax + ay * ay + az * az;
    ax = v2x - v3x; ay = v2y - v3y; az = v2z - v3z;
    float q23 = ax * ax + ay * ay + az * az;

    float mn = fminf(fminf(fminf(q01, q02), fminf(q03, q12)), fminf(q13, q23));
    float el = sqrtf(mn);
    out_alpha[i] = 1.0f - expf(-d * el);

    unsigned int db = __float_as_uint(d);
    atomicMax(vd + idx.x, db);
    atomicMax(vd + idx.y, db);
    atomicMax(vd + idx.z, db);
    atomicMax(vd + idx.w, db);
}

// ---------------- launch ----------------

extern "C" void kernel_launch(void* const* d_in, const int* in_sizes, int n_in,
                              void* d_out, int out_size, void* d_ws, size_t ws_size,
                              hipStream_t stream) {
    const float* verts   = (const float*)d_in[0];
    const int*   indices = (const int*)d_in[1];
    const float* density = (const float*)d_in[2];
    int T = in_sizes[2];        // 4,000,000 tets
    int V = in_sizes[0] / 3;    // 1,000,000 vertices

    float* out       = (float*)d_out;
    float* out_area  = out;
    float* out_alpha = out + (size_t)T;
    unsigned int* vd = (unsigned int*)(out + 2 * (size_t)T);

    const int block = 256;
    int n4 = V / 4;

    size_t pairsB = (size_t)NB * BCAP * sizeof(unsigned);        // 64 MB (packed)
    size_t cntB   = (size_t)NB * GPAD * sizeof(unsigned);        // 16 KB (line-padded)
    size_t v4B    = (size_t)V * sizeof(float4);                  // 16 MB

    double mean = 4.0 * (double)T / NB;
    bool capOK = (mean + 12.0 * __builtin_sqrt(mean) <= (double)BCAP);
    bool fastOK = (V % 4 == 0) && (V <= (NB << VSHIFT)) && capOK && d_ws;

    int tetsPerBlock = block * RT * NR;   // 4096
    int nbAct = (V + (1 << VSHIFT) - 1) >> VSHIFT;

    if (fastOK && ws_size >= pairsB + ((cntB + 255) & ~(size_t)255) + v4B) {
        unsigned* pairs  = (unsigned*)d_ws;
        unsigned* gcnt   = (unsigned*)((char*)d_ws + pairsB);
        float4*   verts4 = (float4*)((char*)d_ws + pairsB + ((cntB + 255) & ~(size_t)255));

        int setupN = (V > n4 ? V : n4);
        setup_kernel<<<(setupN + block - 1) / block, block, 0, stream>>>(
            (uint4*)vd, n4, gcnt, verts, verts4, V);

        fused_geom_bin_kernel<<<(T + tetsPerBlock - 1) / tetsPerBlock, block, 0, stream>>>(
            verts4, (const int4*)indices, density, out_area, out_alpha, pairs, gcnt, vd, T);

        bucket_max_kernel<<<nbAct, 1024, 0, stream>>>(pairs, gcnt, vd, V);
    } else if (d_ws && ws_size >= v4B && (V % 4) == 0) {
        // tier-3: round-3 verified path
        float4* verts4 = (float4*)d_ws;
        int setupN = (V > n4 ? V : n4);
        setup_kernel<<<(setupN + block - 1) / block, block, 0, stream>>>(
            (uint4*)vd, n4, nullptr, verts, verts4, V);
        tet_kernel_filter<<<(T + block - 1) / block, block, 0, stream>>>(
            verts4, indices, density, out_area, out_alpha, vd, T);
    } else {
        // tier-4: round-0 verified path
        setup_kernel<<<(n4 + block - 1) / block, block, 0, stream>>>(
            (uint4*)vd, n4, nullptr, nullptr, nullptr, 0);
        tet_kernel_fb<<<(T + block - 1) / block, block, 0, stream>>>(
            verts, (const int4*)indices, density, out_area, out_alpha, vd, T);
    }
}